// Round 6
// baseline (338.071 us; speedup 1.0000x reference)
//
#include <hip/hip_runtime.h>
#include <stdint.h>

// Problem constants (B=2, L=8, N=1024, DIM=512, H=8, DH=64)
#define DIMC 512
#define NSEQ 1024
#define BLT  16        // B*L
#define NHEAD 8
#define DHD  64
#define MTOT (BLT*NSEQ)   // 16384 rows

typedef float f32x4 __attribute__((ext_vector_type(4)));
typedef short s16x8 __attribute__((ext_vector_type(8)));
typedef short s16x4 __attribute__((ext_vector_type(4)));

__device__ __forceinline__ unsigned short f2bf(float f) {
    unsigned int u = __float_as_uint(f);
    u += 0x7fffu + ((u >> 16) & 1u);   // RNE
    return (unsigned short)(u >> 16);
}
__device__ __forceinline__ float bf2f(unsigned short h) {
    return __uint_as_float(((unsigned int)h) << 16);
}

// softmax pre-scale: 1/sqrt(512) * log2(e)  (exp2-domain softmax)
#define QSCALE (0.04419417382415922f * 1.4426950408889634f)

// async global->LDS, 16B per lane. lds base must be wave-uniform.
__device__ __forceinline__ void gll16(const void* g, void* l) {
    __builtin_amdgcn_global_load_lds(
        (const __attribute__((address_space(1))) void*)g,
        (__attribute__((address_space(3))) void*)l, 16, 0, 0);
}

// 16x16x16 bf16 MFMA (K=16): A,B = 4 bf16 (2 VGPRs); C/D = 4 f32
__device__ __forceinline__ f32x4 mfma16_bf16(s16x4 a, s16x4 b, f32x4 c) {
#if __has_builtin(__builtin_amdgcn_mfma_f32_16x16x16bf16_1k)
    return __builtin_amdgcn_mfma_f32_16x16x16bf16_1k(a, b, c, 0, 0, 0);
#else
    asm volatile("v_mfma_f32_16x16x16_bf16 %0, %1, %2, %0"
                 : "+v"(c) : "v"(a), "v"(b));
    return c;
#endif
}

// inline dtype detect: wave ballot over "crazy bf16 exponent" in x's first 128B
__device__ __forceinline__ bool detect_bf16(const unsigned short* x) {
    int t = threadIdx.x & 63;
    unsigned short v = x[2 * t];
    int e = (v >> 7) & 0xFF;
    unsigned long long ball = __ballot(e < 100 || e > 137);
    return __popcll(ball) < 16;
}

// ---------------------------------------------------------------------------
// One-time convert of all inputs to bf16 (straight copy if already bf16).
// ---------------------------------------------------------------------------
struct ConvArgs {
    const void* src[9];
    unsigned short* dst[9];
};

__global__ __launch_bounds__(256) void conv_kernel(ConvArgs a,
                                                   const unsigned short* __restrict__ xdet) {
    const bool isbf = detect_bf16(xdet);
    int b = blockIdx.x;
    int seg, idx;
    if (b < 4096)      { seg = 0; idx = (b * 256 + threadIdx.x) * 8; }
    else if (b < 4608) { int t = b - 4096; seg = 1 + (t >> 7);
                         idx = (((t & 127) * 256) + threadIdx.x) * 8; }
    else               { int i = threadIdx.x * 8; seg = 5 + (i >> 9); idx = i & 511; }
    const void* s = a.src[seg];
    unsigned short* d = a.dst[seg];
    if (isbf) {
        *(uint4*)(d + idx) = *(const uint4*)((const unsigned short*)s + idx);
    } else {
        float4 t0 = *(const float4*)((const float*)s + idx);
        float4 t1 = *(const float4*)((const float*)s + idx + 4);
        ushort4 v0{f2bf(t0.x), f2bf(t0.y), f2bf(t0.z), f2bf(t0.w)};
        ushort4 v1{f2bf(t1.x), f2bf(t1.y), f2bf(t1.z), f2bf(t1.w)};
        *(ushort4*)(d + idx)     = v0;
        *(ushort4*)(d + idx + 4) = v1;
    }
}

// ---------------------------------------------------------------------------
// m97-pattern GEMM core: out = A @ W^T. 128x128 tile, BK=64, pad-0 LDS,
// global_load_lds width=16. 4 waves in 2x2; each wave 4x4 of 16x16x32 MFMA.
// ---------------------------------------------------------------------------
__device__ __forceinline__ void gemm_core_async(
    const unsigned short* __restrict__ Ap, const unsigned short* __restrict__ Wp,
    int mBase, int nBase, unsigned short* Al, unsigned short* Bl, f32x4 acc[4][4])
{
    const int wave = threadIdx.x >> 6;
    const int lane = threadIdx.x & 63;
    const int lr = lane & 15, lg = lane >> 4;
    const int wm = wave >> 1, wn = wave & 1;
    const int srow = lane >> 3;
    const int scol = (lane & 7) * 8;

    #pragma unroll
    for (int a = 0; a < 4; ++a)
        #pragma unroll
        for (int b = 0; b < 4; ++b) acc[a][b] = (f32x4){0.f, 0.f, 0.f, 0.f};

    for (int k0 = 0; k0 < DIMC; k0 += 64) {
        #pragma unroll
        for (int i = 0; i < 4; ++i) {
            int rbase = (wave * 4 + i) * 8;
            gll16(Ap + (long)(mBase + rbase + srow) * DIMC + k0 + scol, Al + rbase * 64);
            gll16(Wp + (long)(nBase + rbase + srow) * DIMC + k0 + scol, Bl + rbase * 64);
        }
        __syncthreads();

        #pragma unroll
        for (int kk = 0; kk < 64; kk += 32) {
            s16x8 af[4], bf_[4];
            #pragma unroll
            for (int a = 0; a < 4; ++a)
                af[a] = *(const s16x8*)&Al[(wm * 64 + a * 16 + lr) * 64 + kk + lg * 8];
            #pragma unroll
            for (int b = 0; b < 4; ++b)
                bf_[b] = *(const s16x8*)&Bl[(wn * 64 + b * 16 + lr) * 64 + kk + lg * 8];
            #pragma unroll
            for (int a = 0; a < 4; ++a)
                #pragma unroll
                for (int b = 0; b < 4; ++b)
                    acc[a][b] = __builtin_amdgcn_mfma_f32_16x16x32_bf16(af[a], bf_[b], acc[a][b], 0, 0, 0);
        }
        __syncthreads();
    }
}

// ---------------------------------------------------------------------------
// Fused QKV projection. z=0: Q (pre-scaled, [bh][n][d]); z=1: K <- x@Wv^T+bv
// (FAITHFUL BUG); z=2: Vt <- x@Wk^T+bk stored transposed [bh][d][n].
// ---------------------------------------------------------------------------
__global__ __launch_bounds__(256) void proj_kernel(
    const unsigned short* __restrict__ xb,
    const unsigned short* __restrict__ Wqb, const unsigned short* __restrict__ Wkb,
    const unsigned short* __restrict__ Wvb,
    const unsigned short* __restrict__ bqb, const unsigned short* __restrict__ bkb,
    const unsigned short* __restrict__ bvb,
    unsigned short* __restrict__ Q, unsigned short* __restrict__ K,
    unsigned short* __restrict__ Vt)
{
    const int z = blockIdx.z;
    const unsigned short* Wp = (z == 0) ? Wqb : ((z == 1) ? Wvb : Wkb);  // bug mapping
    const unsigned short* bp = (z == 0) ? bqb : ((z == 1) ? bvb : bkb);
    unsigned short* outp = (z == 0) ? Q : ((z == 1) ? K : Vt);
    const float oscale = (z == 0) ? QSCALE : 1.0f;

    const int mBase = blockIdx.x * 128;
    const int nBase = blockIdx.y * 128;
    const int lane = threadIdx.x & 63;
    const int lr = lane & 15, lg = lane >> 4;
    const int wm = (threadIdx.x >> 6) >> 1, wn = (threadIdx.x >> 6) & 1;

    __shared__ unsigned short Al[128 * 64];
    __shared__ unsigned short Bl[128 * 64];
    f32x4 acc[4][4];
    gemm_core_async(xb, Wp, mBase, nBase, Al, Bl, acc);

    #pragma unroll
    for (int b = 0; b < 4; ++b) {
        int j = nBase + wn * 64 + b * 16 + lr;
        float bb = bf2f(bp[j]);
        int h = j >> 6, d = j & 63;
        #pragma unroll
        for (int a = 0; a < 4; ++a) {
            int m0 = mBase + wm * 64 + a * 16 + lg * 4;
            int bl = m0 >> 10, n0 = m0 & 1023;
            if (z == 2) {
                ushort4 pk;
                unsigned short* p = (unsigned short*)&pk;
                #pragma unroll
                for (int r = 0; r < 4; ++r) p[r] = f2bf(acc[a][b][r] + bb);
                *(ushort4*)&outp[(((bl << 3) + h) << 16) + (d << 10) + n0] = pk;
            } else {
                #pragma unroll
                for (int r = 0; r < 4; ++r) {
                    float v = (acc[a][b][r] + bb) * oscale;
                    outp[(((bl << 3) + h) << 16) + ((n0 + r) << 6) + d] = f2bf(v);
                }
            }
        }
    }
}

// ---------------------------------------------------------------------------
// Final projection: out = inter @ Wo^T + bo, output dtype via inline detect.
// ---------------------------------------------------------------------------
__global__ __launch_bounds__(256) void out_gemm_kernel(
    const unsigned short* __restrict__ inter, const unsigned short* __restrict__ Wob,
    const unsigned short* __restrict__ bob, void* __restrict__ outp,
    const unsigned short* __restrict__ xdet)
{
    const bool isbf = detect_bf16(xdet);
    const int mBase = blockIdx.x * 128;
    const int nBase = blockIdx.y * 128;
    const int lane = threadIdx.x & 63;
    const int lr = lane & 15, lg = lane >> 4;
    const int wm = (threadIdx.x >> 6) >> 1, wn = (threadIdx.x >> 6) & 1;

    __shared__ unsigned short Al[128 * 64];
    __shared__ unsigned short Bl[128 * 64];
    f32x4 acc[4][4];
    gemm_core_async(inter, Wob, mBase, nBase, Al, Bl, acc);

    #pragma unroll
    for (int b = 0; b < 4; ++b) {
        int j = nBase + wn * 64 + b * 16 + lr;
        float bb = bf2f(bob[j]);
        #pragma unroll
        for (int a = 0; a < 4; ++a) {
            #pragma unroll
            for (int r = 0; r < 4; ++r) {
                long m = mBase + wm * 64 + a * 16 + lg * 4 + r;
                float v = acc[a][b][r] + bb;
                if (isbf) ((unsigned short*)outp)[m * DIMC + j] = f2bf(v);
                else      ((float*)outp)[m * DIMC + j] = v;
            }
        }
    }
}

// ---------------------------------------------------------------------------
// Flash attention, barrier-free / LDS-free (R5 post-mortem: latency-bound at
// 1 wave/SIMD; barriers + staging serialize). K and V^T fragments are read
// DIRECTLY from global: per-head K+V = 256 KB; blockIdx = qt*128+bh puts all
// of a bh's blocks on one XCD (bh%8) -> 16 bh x 256 KB = 4 MB = per-XCD L2;
// co-resident blocks on a CU share the same bh -> L1 filters re-reads.
// Wave = 32 q-rows (2 groups), block = 4 waves = 128 q, grid 1024. No LDS,
// no __syncthreads: waves independent, kt-loop software-pipelineable.
//   S^T = K·Q^T (C-layout == x16 B-operand layout, P^T register-resident)
//   O^T = V^T·P^T via x16 MFMAs (A-frags = 8B direct loads from Vt).
// Q pre-scaled by QSCALE; single-pass exp2 softmax (R3-verified bounds).
// ---------------------------------------------------------------------------
__global__ __launch_bounds__(256) void attn_kernel(
    const unsigned short* __restrict__ Q, const unsigned short* __restrict__ K,
    const unsigned short* __restrict__ Vt, unsigned short* __restrict__ inter)
{
    const int b = blockIdx.x;          // 0..1023
    const int bh = b & 127;            // XCD = bh % 8  (L2 locality)
    const int qt = b >> 7;             // 0..7 (128-q tile)
    const int wave = threadIdx.x >> 6;
    const int lane = threadIdx.x & 63;
    const int lr = lane & 15;
    const int lg = lane >> 4;

    const unsigned short* Qb = Q + (long)bh * (NSEQ * DHD);
    const unsigned short* Kb = K + (long)bh * (NSEQ * DHD);
    const unsigned short* Vb = Vt + (long)bh * (NSEQ * DHD);   // [d][n]
    const int qbase = qt * 128 + wave * 32;

    // Q B-frags for 2 q-groups x 2 k-halves (held in regs all 16 kt)
    s16x8 qf[2][2];
    #pragma unroll
    for (int g = 0; g < 2; ++g)
        #pragma unroll
        for (int kk = 0; kk < 2; ++kk)
            qf[g][kk] = *(const s16x8*)&Qb[(qbase + g * 16 + lr) * DHD + kk * 32 + lg * 8];

    f32x4 o[2][4];   // O^T per q-group: lane holds O^T[d=m*16+lg*4+r][q=lr]
    #pragma unroll
    for (int g = 0; g < 2; ++g)
        #pragma unroll
        for (int m = 0; m < 4; ++m) o[g][m] = (f32x4){0.f, 0.f, 0.f, 0.f};
    float l_acc[2] = {0.f, 0.f};

    #pragma unroll 2
    for (int kt = 0; kt < 16; ++kt) {
        // K A-frags (16B contiguous per lane, L1/L2-served)
        s16x8 af[2][4];
        #pragma unroll
        for (int kk = 0; kk < 2; ++kk)
            #pragma unroll
            for (int c = 0; c < 4; ++c)
                af[kk][c] = *(const s16x8*)&Kb[(kt * 64 + c * 16 + lr) * DHD + kk * 32 + lg * 8];

        // S^T = K·Q^T
        f32x4 s[2][4];
        #pragma unroll
        for (int g = 0; g < 2; ++g)
            #pragma unroll
            for (int c = 0; c < 4; ++c) s[g][c] = (f32x4){0.f, 0.f, 0.f, 0.f};
        #pragma unroll
        for (int kk = 0; kk < 2; ++kk)
            #pragma unroll
            for (int g = 0; g < 2; ++g)
                #pragma unroll
                for (int c = 0; c < 4; ++c)
                    s[g][c] = __builtin_amdgcn_mfma_f32_16x16x32_bf16(af[kk][c], qf[g][kk], s[g][c], 0, 0, 0);

        // P^T = exp2(S^T) in-register; pack bf16 B-frags; accumulate l per g
        s16x4 pb[2][4];
        #pragma unroll
        for (int g = 0; g < 2; ++g)
            #pragma unroll
            for (int c = 0; c < 4; ++c) {
                float p0 = __builtin_exp2f(s[g][c][0]);
                float p1 = __builtin_exp2f(s[g][c][1]);
                float p2 = __builtin_exp2f(s[g][c][2]);
                float p3 = __builtin_exp2f(s[g][c][3]);
                l_acc[g] += (p0 + p1) + (p2 + p3);
                unsigned int u0 = __float_as_uint(p0) + 0x8000u;
                unsigned int u1 = __float_as_uint(p1) + 0x8000u;
                unsigned int u2 = __float_as_uint(p2) + 0x8000u;
                unsigned int u3 = __float_as_uint(p3) + 0x8000u;
                union { s16x4 v; unsigned int u[2]; } pk;
                pk.u[0] = __builtin_amdgcn_perm(u1, u0, 0x07060302u);
                pk.u[1] = __builtin_amdgcn_perm(u3, u2, 0x07060302u);
                pb[g][c] = pk.v;
            }

        // O^T += V^T·P^T : V A-frags direct 8B loads, reused by both q-groups
        #pragma unroll
        for (int c = 0; c < 4; ++c) {
            s16x4 va[4];
            #pragma unroll
            for (int m = 0; m < 4; ++m)
                va[m] = *(const s16x4*)&Vb[(m * 16 + lr) * NSEQ + kt * 64 + c * 16 + lg * 4];
            #pragma unroll
            for (int g = 0; g < 2; ++g)
                #pragma unroll
                for (int m = 0; m < 4; ++m)
                    o[g][m] = mfma16_bf16(va[m], pb[g][c], o[g][m]);
        }
    }

    // epilogue per q-group: l reduce over lg, normalize, store merged-head
    const int bl = bh >> 3, h = bh & 7;
    #pragma unroll
    for (int g = 0; g < 2; ++g) {
        float l = l_acc[g];
        l += __shfl_xor(l, 16);
        l += __shfl_xor(l, 32);
        float inv = 1.f / l;
        const int n = qbase + g * 16 + lr;
        #pragma unroll
        for (int m = 0; m < 4; ++m) {
            ushort4 pk;
            unsigned short* p = (unsigned short*)&pk;
            #pragma unroll
            for (int r = 0; r < 4; ++r) p[r] = f2bf(o[g][m][r] * inv);
            *(ushort4*)&inter[((long)(bl * NSEQ + n)) * DIMC + h * 64 + m * 16 + lg * 4] = pk;
        }
    }
}

// ---------------------------------------------------------------------------
extern "C" void kernel_launch(void* const* d_in, const int* in_sizes, int n_in,
                              void* d_out, int out_size, void* d_ws, size_t ws_size,
                              hipStream_t stream) {
    const void* x  = d_in[0];
    const void* Wq = d_in[1]; const void* bq = d_in[2];
    const void* Wk = d_in[3]; const void* bk = d_in[4];
    const void* Wv = d_in[5]; const void* bv = d_in[6];
    const void* Wo = d_in[7]; const void* bo = d_in[8];

    char* ws = (char*)d_ws;
    unsigned short* xb  = (unsigned short*)ws;              // also 'inter' (aliased)
    unsigned short* Q   = xb + (long)MTOT * DIMC;
    unsigned short* K   = Q  + (long)MTOT * DIMC;
    unsigned short* Vt  = K  + (long)MTOT * DIMC;
    unsigned short* Wqb = Vt + (long)MTOT * DIMC;
    unsigned short* Wkb = Wqb + DIMC * DIMC;
    unsigned short* Wvb = Wkb + DIMC * DIMC;
    unsigned short* Wob = Wvb + DIMC * DIMC;
    unsigned short* bqb = Wob + DIMC * DIMC;
    unsigned short* bkb = bqb + DIMC;
    unsigned short* bvb = bkb + DIMC;
    unsigned short* bob = bvb + DIMC;

    ConvArgs ca;
    ca.src[0] = x;  ca.src[1] = Wq; ca.src[2] = Wk; ca.src[3] = Wv; ca.src[4] = Wo;
    ca.src[5] = bq; ca.src[6] = bk; ca.src[7] = bv; ca.src[8] = bo;
    ca.dst[0] = xb;  ca.dst[1] = Wqb; ca.dst[2] = Wkb; ca.dst[3] = Wvb; ca.dst[4] = Wob;
    ca.dst[5] = bqb; ca.dst[6] = bkb; ca.dst[7] = bvb; ca.dst[8] = bob;
    conv_kernel<<<4609, 256, 0, stream>>>(ca, (const unsigned short*)x);

    dim3 gp(MTOT / 128, DIMC / 128, 3);
    proj_kernel<<<gp, 256, 0, stream>>>(xb, Wqb, Wkb, Wvb, bqb, bkb, bvb, Q, K, Vt);

    attn_kernel<<<8 * 128, 256, 0, stream>>>(Q, K, Vt, xb /*inter*/);

    dim3 go(MTOT / 128, DIMC / 128);
    out_gemm_kernel<<<go, 256, 0, stream>>>(xb /*inter*/, Wob, bob, d_out,
                                            (const unsigned short*)x);
}

// Round 7
// 224.057 us; speedup vs baseline: 1.5089x; 1.5089x over previous
//
#include <hip/hip_runtime.h>
#include <stdint.h>

// Problem constants (B=2, L=8, N=1024, DIM=512, H=8, DH=64)
#define DIMC 512
#define NSEQ 1024
#define BLT  16        // B*L
#define NHEAD 8
#define DHD  64
#define MTOT (BLT*NSEQ)   // 16384 rows

typedef float f32x4 __attribute__((ext_vector_type(4)));
typedef short s16x8 __attribute__((ext_vector_type(8)));
typedef short s16x4 __attribute__((ext_vector_type(4)));

__device__ __forceinline__ unsigned short f2bf(float f) {
    unsigned int u = __float_as_uint(f);
    u += 0x7fffu + ((u >> 16) & 1u);   // RNE
    return (unsigned short)(u >> 16);
}
__device__ __forceinline__ float bf2f(unsigned short h) {
    return __uint_as_float(((unsigned int)h) << 16);
}

// softmax pre-scale: 1/sqrt(512) * log2(e)  (exp2-domain softmax)
#define QSCALE (0.04419417382415922f * 1.4426950408889634f)

// async global->LDS, 16B per lane. lds base must be wave-uniform.
__device__ __forceinline__ void gll16(const void* g, void* l) {
    __builtin_amdgcn_global_load_lds(
        (const __attribute__((address_space(1))) void*)g,
        (__attribute__((address_space(3))) void*)l, 16, 0, 0);
}

// 16x16x16 bf16 MFMA (K=16): A,B = 4 bf16 (2 VGPRs); C/D = 4 f32
__device__ __forceinline__ f32x4 mfma16_bf16(s16x4 a, s16x4 b, f32x4 c) {
#if __has_builtin(__builtin_amdgcn_mfma_f32_16x16x16bf16_1k)
    return __builtin_amdgcn_mfma_f32_16x16x16bf16_1k(a, b, c, 0, 0, 0);
#else
    asm volatile("v_mfma_f32_16x16x16_bf16 %0, %1, %2, %0"
                 : "+v"(c) : "v"(a), "v"(b));
    return c;
#endif
}

// inline dtype detect: wave ballot over "crazy bf16 exponent" in x's first 128B
__device__ __forceinline__ bool detect_bf16(const unsigned short* x) {
    int t = threadIdx.x & 63;
    unsigned short v = x[2 * t];
    int e = (v >> 7) & 0xFF;
    unsigned long long ball = __ballot(e < 100 || e > 137);
    return __popcll(ball) < 16;
}

// ---------------------------------------------------------------------------
// One-time convert of all inputs to bf16 (straight copy if already bf16).
// ---------------------------------------------------------------------------
struct ConvArgs {
    const void* src[9];
    unsigned short* dst[9];
};

__global__ __launch_bounds__(256) void conv_kernel(ConvArgs a,
                                                   const unsigned short* __restrict__ xdet) {
    const bool isbf = detect_bf16(xdet);
    int b = blockIdx.x;
    int seg, idx;
    if (b < 4096)      { seg = 0; idx = (b * 256 + threadIdx.x) * 8; }
    else if (b < 4608) { int t = b - 4096; seg = 1 + (t >> 7);
                         idx = (((t & 127) * 256) + threadIdx.x) * 8; }
    else               { int i = threadIdx.x * 8; seg = 5 + (i >> 9); idx = i & 511; }
    const void* s = a.src[seg];
    unsigned short* d = a.dst[seg];
    if (isbf) {
        *(uint4*)(d + idx) = *(const uint4*)((const unsigned short*)s + idx);
    } else {
        float4 t0 = *(const float4*)((const float*)s + idx);
        float4 t1 = *(const float4*)((const float*)s + idx + 4);
        ushort4 v0{f2bf(t0.x), f2bf(t0.y), f2bf(t0.z), f2bf(t0.w)};
        ushort4 v1{f2bf(t1.x), f2bf(t1.y), f2bf(t1.z), f2bf(t1.w)};
        *(ushort4*)(d + idx)     = v0;
        *(ushort4*)(d + idx + 4) = v1;
    }
}

// ---------------------------------------------------------------------------
// m97-pattern GEMM core: out = A @ W^T. 128x128 tile, BK=64, pad-0 LDS,
// global_load_lds width=16. 4 waves in 2x2; each wave 4x4 of 16x16x32 MFMA.
// ---------------------------------------------------------------------------
__device__ __forceinline__ void gemm_core_async(
    const unsigned short* __restrict__ Ap, const unsigned short* __restrict__ Wp,
    int mBase, int nBase, unsigned short* Al, unsigned short* Bl, f32x4 acc[4][4])
{
    const int wave = threadIdx.x >> 6;
    const int lane = threadIdx.x & 63;
    const int lr = lane & 15, lg = lane >> 4;
    const int wm = wave >> 1, wn = wave & 1;
    const int srow = lane >> 3;
    const int scol = (lane & 7) * 8;

    #pragma unroll
    for (int a = 0; a < 4; ++a)
        #pragma unroll
        for (int b = 0; b < 4; ++b) acc[a][b] = (f32x4){0.f, 0.f, 0.f, 0.f};

    for (int k0 = 0; k0 < DIMC; k0 += 64) {
        #pragma unroll
        for (int i = 0; i < 4; ++i) {
            int rbase = (wave * 4 + i) * 8;
            gll16(Ap + (long)(mBase + rbase + srow) * DIMC + k0 + scol, Al + rbase * 64);
            gll16(Wp + (long)(nBase + rbase + srow) * DIMC + k0 + scol, Bl + rbase * 64);
        }
        __syncthreads();

        #pragma unroll
        for (int kk = 0; kk < 64; kk += 32) {
            s16x8 af[4], bf_[4];
            #pragma unroll
            for (int a = 0; a < 4; ++a)
                af[a] = *(const s16x8*)&Al[(wm * 64 + a * 16 + lr) * 64 + kk + lg * 8];
            #pragma unroll
            for (int b = 0; b < 4; ++b)
                bf_[b] = *(const s16x8*)&Bl[(wn * 64 + b * 16 + lr) * 64 + kk + lg * 8];
            #pragma unroll
            for (int a = 0; a < 4; ++a)
                #pragma unroll
                for (int b = 0; b < 4; ++b)
                    acc[a][b] = __builtin_amdgcn_mfma_f32_16x16x32_bf16(af[a], bf_[b], acc[a][b], 0, 0, 0);
        }
        __syncthreads();
    }
}

// ---------------------------------------------------------------------------
// Fused QKV projection. z=0: Q (pre-scaled, [bh][n][d]); z=1: K <- x@Wv^T+bv
// (FAITHFUL BUG); z=2: Vt <- x@Wk^T+bk stored transposed [bh][d][n].
// ---------------------------------------------------------------------------
__global__ __launch_bounds__(256) void proj_kernel(
    const unsigned short* __restrict__ xb,
    const unsigned short* __restrict__ Wqb, const unsigned short* __restrict__ Wkb,
    const unsigned short* __restrict__ Wvb,
    const unsigned short* __restrict__ bqb, const unsigned short* __restrict__ bkb,
    const unsigned short* __restrict__ bvb,
    unsigned short* __restrict__ Q, unsigned short* __restrict__ K,
    unsigned short* __restrict__ Vt)
{
    const int z = blockIdx.z;
    const unsigned short* Wp = (z == 0) ? Wqb : ((z == 1) ? Wvb : Wkb);  // bug mapping
    const unsigned short* bp = (z == 0) ? bqb : ((z == 1) ? bvb : bkb);
    unsigned short* outp = (z == 0) ? Q : ((z == 1) ? K : Vt);
    const float oscale = (z == 0) ? QSCALE : 1.0f;

    const int mBase = blockIdx.x * 128;
    const int nBase = blockIdx.y * 128;
    const int lane = threadIdx.x & 63;
    const int lr = lane & 15, lg = lane >> 4;
    const int wm = (threadIdx.x >> 6) >> 1, wn = (threadIdx.x >> 6) & 1;

    __shared__ unsigned short Al[128 * 64];
    __shared__ unsigned short Bl[128 * 64];
    f32x4 acc[4][4];
    gemm_core_async(xb, Wp, mBase, nBase, Al, Bl, acc);

    #pragma unroll
    for (int b = 0; b < 4; ++b) {
        int j = nBase + wn * 64 + b * 16 + lr;
        float bb = bf2f(bp[j]);
        int h = j >> 6, d = j & 63;
        #pragma unroll
        for (int a = 0; a < 4; ++a) {
            int m0 = mBase + wm * 64 + a * 16 + lg * 4;
            int bl = m0 >> 10, n0 = m0 & 1023;
            if (z == 2) {
                ushort4 pk;
                unsigned short* p = (unsigned short*)&pk;
                #pragma unroll
                for (int r = 0; r < 4; ++r) p[r] = f2bf(acc[a][b][r] + bb);
                *(ushort4*)&outp[(((bl << 3) + h) << 16) + (d << 10) + n0] = pk;
            } else {
                #pragma unroll
                for (int r = 0; r < 4; ++r) {
                    float v = (acc[a][b][r] + bb) * oscale;
                    outp[(((bl << 3) + h) << 16) + ((n0 + r) << 6) + d] = f2bf(v);
                }
            }
        }
    }
}

// ---------------------------------------------------------------------------
// Final projection: out = inter @ Wo^T + bo, output dtype via inline detect.
// ---------------------------------------------------------------------------
__global__ __launch_bounds__(256) void out_gemm_kernel(
    const unsigned short* __restrict__ inter, const unsigned short* __restrict__ Wob,
    const unsigned short* __restrict__ bob, void* __restrict__ outp,
    const unsigned short* __restrict__ xdet)
{
    const bool isbf = detect_bf16(xdet);
    const int mBase = blockIdx.x * 128;
    const int nBase = blockIdx.y * 128;
    const int lane = threadIdx.x & 63;
    const int lr = lane & 15, lg = lane >> 4;
    const int wm = (threadIdx.x >> 6) >> 1, wn = (threadIdx.x >> 6) & 1;

    __shared__ unsigned short Al[128 * 64];
    __shared__ unsigned short Bl[128 * 64];
    f32x4 acc[4][4];
    gemm_core_async(inter, Wob, mBase, nBase, Al, Bl, acc);

    #pragma unroll
    for (int b = 0; b < 4; ++b) {
        int j = nBase + wn * 64 + b * 16 + lr;
        float bb = bf2f(bob[j]);
        #pragma unroll
        for (int a = 0; a < 4; ++a) {
            #pragma unroll
            for (int r = 0; r < 4; ++r) {
                long m = mBase + wm * 64 + a * 16 + lg * 4 + r;
                float v = acc[a][b][r] + bb;
                if (isbf) ((unsigned short*)outp)[m * DIMC + j] = f2bf(v);
                else      ((float*)outp)[m * DIMC + j] = v;
            }
        }
    }
}

// ---------------------------------------------------------------------------
// Flash attention v7: LDS staging (R4, coalesced) + 2x q-amortization (R5's
// idea at half strength to keep occupancy) . Wave = 32 q-rows (2 B-frag
// groups), block = 128 q, grid = 1024 (4/CU), __launch_bounds__(256,3)
// -> 3 waves/SIMD, ~3 co-resident blocks hide the per-kt barrier.
// R6 post-mortem: direct-global frags are uncoalesced at L1 -> must stage.
//   S^T = K·Q^T (C-layout == x16 B-operand layout, P^T register-resident)
//   O^T = V^T·P^T via x16 MFMAs, A-frags contiguous b64 from swizzled Vl.
// Q pre-scaled by QSCALE; single-pass exp2 softmax (R3-verified bounds).
// blockIdx = qt*128 + bh  ->  XCD = bh%8 (all blocks of a bh on one XCD).
// ---------------------------------------------------------------------------
#define SWZ(row, col) ((row) * 64 + ((col) ^ (((row) & 7) * 8)))

__global__ __launch_bounds__(256, 3) void attn_kernel(
    const unsigned short* __restrict__ Q, const unsigned short* __restrict__ K,
    const unsigned short* __restrict__ Vt, unsigned short* __restrict__ inter)
{
    const int b = blockIdx.x;          // 0..1023
    const int bh = b & 127;            // XCD = bh % 8  (L2 locality)
    const int qt = b >> 7;             // 0..7 (128-q tile)
    const int wave = threadIdx.x >> 6;
    const int lane = threadIdx.x & 63;
    const int lr = lane & 15;
    const int lg = lane >> 4;

    const unsigned short* Qb = Q + (long)bh * (NSEQ * DHD);
    const int qbase = qt * 128 + wave * 32;

    // Q B-frags for 2 q-groups x 2 k-halves (held in regs all 16 kt)
    s16x8 qf[2][2];
    #pragma unroll
    for (int g = 0; g < 2; ++g)
        #pragma unroll
        for (int kk = 0; kk < 2; ++kk)
            qf[g][kk] = *(const s16x8*)&Qb[(qbase + g * 16 + lr) * DHD + kk * 32 + lg * 8];

    __shared__ unsigned short Kl[64 * 64];     // [key][d], swizzled
    __shared__ unsigned short Vl[64 * 64];     // [d][key], swizzled

    f32x4 o[2][4];   // O^T per q-group: lane holds O^T[d=m*16+lg*4+r][q=lr]
    #pragma unroll
    for (int g = 0; g < 2; ++g)
        #pragma unroll
        for (int m = 0; m < 4; ++m) o[g][m] = (f32x4){0.f, 0.f, 0.f, 0.f};
    float l_acc[2] = {0.f, 0.f};

    for (int kt = 0; kt < 16; ++kt) {
        const unsigned short* Kb = K + (long)bh * (NSEQ * DHD) + kt * 64 * DHD;
        const unsigned short* Vb = Vt + (long)bh * (NSEQ * DHD) + kt * 64;   // [d][n]

        #pragma unroll
        for (int i = 0; i < 2; ++i) {
            int f = threadIdx.x + 256 * i;
            int row = f >> 3, c8 = (f & 7) * 8;
            *(uint4*)&Kl[SWZ(row, c8)] = *(const uint4*)&Kb[row * DHD + c8];
            *(uint4*)&Vl[SWZ(row, c8)] = *(const uint4*)&Vb[row * NSEQ + c8];
        }
        __syncthreads();

        // S^T = K·Q^T : K A-frags read ONCE, reused by both q-groups
        f32x4 s[2][4];
        #pragma unroll
        for (int g = 0; g < 2; ++g)
            #pragma unroll
            for (int c = 0; c < 4; ++c) s[g][c] = (f32x4){0.f, 0.f, 0.f, 0.f};
        #pragma unroll
        for (int kk = 0; kk < 2; ++kk) {
            s16x8 af[4];
            #pragma unroll
            for (int c = 0; c < 4; ++c)
                af[c] = *(const s16x8*)&Kl[SWZ(c * 16 + lr, kk * 32 + lg * 8)];
            #pragma unroll
            for (int g = 0; g < 2; ++g)
                #pragma unroll
                for (int c = 0; c < 4; ++c)
                    s[g][c] = __builtin_amdgcn_mfma_f32_16x16x32_bf16(af[c], qf[g][kk], s[g][c], 0, 0, 0);
        }

        // P^T = exp2(S^T) in-register; pack bf16 B-frags; accumulate l per g
        s16x4 pb[2][4];
        #pragma unroll
        for (int g = 0; g < 2; ++g)
            #pragma unroll
            for (int c = 0; c < 4; ++c) {
                float p0 = __builtin_exp2f(s[g][c][0]);
                float p1 = __builtin_exp2f(s[g][c][1]);
                float p2 = __builtin_exp2f(s[g][c][2]);
                float p3 = __builtin_exp2f(s[g][c][3]);
                l_acc[g] += (p0 + p1) + (p2 + p3);
                unsigned int u0 = __float_as_uint(p0) + 0x8000u;
                unsigned int u1 = __float_as_uint(p1) + 0x8000u;
                unsigned int u2 = __float_as_uint(p2) + 0x8000u;
                unsigned int u3 = __float_as_uint(p3) + 0x8000u;
                union { s16x4 v; unsigned int u[2]; } pk;
                pk.u[0] = __builtin_amdgcn_perm(u1, u0, 0x07060302u);
                pk.u[1] = __builtin_amdgcn_perm(u3, u2, 0x07060302u);
                pb[g][c] = pk.v;
            }

        // O^T += V^T·P^T : V A-frags read ONCE per c, reused by both q-groups
        #pragma unroll
        for (int c = 0; c < 4; ++c) {
            s16x4 va[4];
            #pragma unroll
            for (int m = 0; m < 4; ++m)
                va[m] = *(const s16x4*)&Vl[SWZ(m * 16 + lr, c * 16 + lg * 4)];
            #pragma unroll
            for (int g = 0; g < 2; ++g)
                #pragma unroll
                for (int m = 0; m < 4; ++m)
                    o[g][m] = mfma16_bf16(va[m], pb[g][c], o[g][m]);
        }
        __syncthreads();   // before next tile's staging overwrites Kl/Vl
    }

    // epilogue per q-group: l reduce over lg, normalize, store merged-head
    const int bl = bh >> 3, h = bh & 7;
    #pragma unroll
    for (int g = 0; g < 2; ++g) {
        float l = l_acc[g];
        l += __shfl_xor(l, 16);
        l += __shfl_xor(l, 32);
        float inv = 1.f / l;
        const int n = qbase + g * 16 + lr;
        #pragma unroll
        for (int m = 0; m < 4; ++m) {
            ushort4 pk;
            unsigned short* p = (unsigned short*)&pk;
            #pragma unroll
            for (int r = 0; r < 4; ++r) p[r] = f2bf(o[g][m][r] * inv);
            *(ushort4*)&inter[((long)(bl * NSEQ + n)) * DIMC + h * 64 + m * 16 + lg * 4] = pk;
        }
    }
}

// ---------------------------------------------------------------------------
extern "C" void kernel_launch(void* const* d_in, const int* in_sizes, int n_in,
                              void* d_out, int out_size, void* d_ws, size_t ws_size,
                              hipStream_t stream) {
    const void* x  = d_in[0];
    const void* Wq = d_in[1]; const void* bq = d_in[2];
    const void* Wk = d_in[3]; const void* bk = d_in[4];
    const void* Wv = d_in[5]; const void* bv = d_in[6];
    const void* Wo = d_in[7]; const void* bo = d_in[8];

    char* ws = (char*)d_ws;
    unsigned short* xb  = (unsigned short*)ws;              // also 'inter' (aliased)
    unsigned short* Q   = xb + (long)MTOT * DIMC;
    unsigned short* K   = Q  + (long)MTOT * DIMC;
    unsigned short* Vt  = K  + (long)MTOT * DIMC;
    unsigned short* Wqb = Vt + (long)MTOT * DIMC;
    unsigned short* Wkb = Wqb + DIMC * DIMC;
    unsigned short* Wvb = Wkb + DIMC * DIMC;
    unsigned short* Wob = Wvb + DIMC * DIMC;
    unsigned short* bqb = Wob + DIMC * DIMC;
    unsigned short* bkb = bqb + DIMC;
    unsigned short* bvb = bkb + DIMC;
    unsigned short* bob = bvb + DIMC;

    ConvArgs ca;
    ca.src[0] = x;  ca.src[1] = Wq; ca.src[2] = Wk; ca.src[3] = Wv; ca.src[4] = Wo;
    ca.src[5] = bq; ca.src[6] = bk; ca.src[7] = bv; ca.src[8] = bo;
    ca.dst[0] = xb;  ca.dst[1] = Wqb; ca.dst[2] = Wkb; ca.dst[3] = Wvb; ca.dst[4] = Wob;
    ca.dst[5] = bqb; ca.dst[6] = bkb; ca.dst[7] = bvb; ca.dst[8] = bob;
    conv_kernel<<<4609, 256, 0, stream>>>(ca, (const unsigned short*)x);

    dim3 gp(MTOT / 128, DIMC / 128, 3);
    proj_kernel<<<gp, 256, 0, stream>>>(xb, Wqb, Wkb, Wvb, bqb, bkb, bvb, Q, K, Vt);

    attn_kernel<<<8 * 128, 256, 0, stream>>>(Q, K, Vt, xb /*inter*/);

    dim3 go(MTOT / 128, DIMC / 128);
    out_gemm_kernel<<<go, 256, 0, stream>>>(xb /*inter*/, Wob, bob, d_out,
                                            (const unsigned short*)x);
}